// Round 4
// baseline (950.846 us; speedup 1.0000x reference)
//
#include <hip/hip_runtime.h>

// LSTM cell: fp32 inputs, fp32 output (comparison is bf16-lenient).
// gates[B,3H] = x@Wx^T + h@Wh^T + biases; new_c = sig(gf)*c + sig(gi)*tanh(gg).
// M=16384, N=1024 x 3 gates, K=2048. MFMA bf16 16x16x32; fp32 inputs converted
// to bf16 in registers during LDS staging.
// Tile: block = 128M x 64N x 3 gates, 256 thr = 4 waves (2x2), wave = 64x32x3.

#define HS      1024
#define K_TOTAL 2048
#define BK      32

typedef __bf16 bf16;
typedef bf16  bf16x4 __attribute__((ext_vector_type(4)));
typedef bf16  bf16x8 __attribute__((ext_vector_type(8)));
typedef float f32x4  __attribute__((ext_vector_type(4)));

// Stage one 64x32 fp32 panel (row stride ld) into bf16 LDS [64][32].
__device__ __forceinline__ void stage64x32(const float* __restrict__ src, size_t ld,
                                           bf16* __restrict__ dst, int tid) {
#pragma unroll
  for (int b = 0; b < 2; ++b) {
    const int cchunk = tid + b * 256;       // 512 float4-chunks per panel
    const int row = cchunk >> 3;            // 0..63
    const int col = (cchunk & 7) * 4;       // 0..28
    const f32x4 v = *(const f32x4*)(src + (size_t)row * ld + col);
    bf16x4 o;
    o[0] = (bf16)v[0]; o[1] = (bf16)v[1]; o[2] = (bf16)v[2]; o[3] = (bf16)v[3];
    *(bf16x4*)(dst + row * 32 + col) = o;
  }
}

__global__ __launch_bounds__(256, 1) void lstm_fused(
    const float* __restrict__ x, const float* __restrict__ h,
    const float* __restrict__ c,
    const float* __restrict__ w_ii, const float* __restrict__ w_hi,
    const float* __restrict__ w_if, const float* __restrict__ w_hf,
    const float* __restrict__ w_ig, const float* __restrict__ w_hg,
    const float* __restrict__ b_ii, const float* __restrict__ b_hi,
    const float* __restrict__ b_if, const float* __restrict__ b_hf,
    const float* __restrict__ b_ig, const float* __restrict__ b_hg,
    float* __restrict__ out)
{
  __shared__ bf16 smem[4096 + 3 * 2048];  // As[128][32], Bs[3][64][32]
  bf16* As = smem;
  bf16* Bs = smem + 4096;

  const int tid  = threadIdx.x;
  const int lane = tid & 63;
  const int wave = tid >> 6;

  const int bid = blockIdx.x;
  const int mt  = bid & 127;   // consecutive bids share the N-tile (weight L2 reuse)
  const int nt  = bid >> 7;
  const int m0  = mt * 128;
  const int n0  = nt * 64;
  const int wm  = (wave & 1) * 64;
  const int wn  = (wave >> 1) * 32;

  // ---- C/D layout self-calibration (verified no-op insurance) ----
  //   probe1: A[m][0]=m+1, B[0][n]=1   => D1[m][n] = m+1
  //   probe2: A[m][0]=1,   B[0][n]=n+1 => D2[m][n] = n+1
  bf16x8 pa1 = {}, pa2 = {}, pb1 = {}, pb2 = {};
  if ((lane >> 4) == 0) {
    pa1[0] = (bf16)(float)((lane & 15) + 1);
    pa2[0] = (bf16)1.0f;
    pb1[0] = (bf16)1.0f;
    pb2[0] = (bf16)(float)((lane & 15) + 1);
  }
  f32x4 zf = {};
  f32x4 d1 = __builtin_amdgcn_mfma_f32_16x16x32_bf16(pa1, pb1, zf, 0, 0, 0);
  f32x4 d2 = __builtin_amdgcn_mfma_f32_16x16x32_bf16(pa2, pb2, zf, 0, 0, 0);
  int mhat[4], nhat[4];
#pragma unroll
  for (int r = 0; r < 4; ++r) {
    mhat[r] = ((int)(d1[r] + 0.5f) - 1) & 15;  // row (m) of this (lane,reg)
    nhat[r] = ((int)(d2[r] + 0.5f) - 1) & 15;  // col (n) of this (lane,reg)
  }

  f32x4 acc[3][4][2] = {};  // [gate][m-frag][n-frag]

  for (int k0 = 0; k0 < K_TOTAL; k0 += BK) {
    const float* Ag;
    const float* w0;
    const float* w1;
    const float* w2;
    int kl;
    if (k0 < 1024) { Ag = x; w0 = w_ii; w1 = w_if; w2 = w_ig; kl = k0; }
    else           { Ag = h; w0 = w_hi; w1 = w_hf; w2 = w_hg; kl = k0 - 1024; }

    stage64x32(Ag + (size_t)m0 * HS + kl,        HS, As,        tid);
    stage64x32(Ag + (size_t)(m0 + 64) * HS + kl, HS, As + 2048, tid);
    stage64x32(w0 + (size_t)n0 * HS + kl,        HS, Bs,        tid);
    stage64x32(w1 + (size_t)n0 * HS + kl,        HS, Bs + 2048, tid);
    stage64x32(w2 + (size_t)n0 * HS + kl,        HS, Bs + 4096, tid);

    __syncthreads();

    const int fr = lane & 15;
    const int fk = (lane >> 4) * 8;

    bf16x8 af[4];
#pragma unroll
    for (int i = 0; i < 4; ++i)
      af[i] = *(const bf16x8*)(As + (wm + i * 16 + fr) * 32 + fk);

#pragma unroll
    for (int g = 0; g < 3; ++g) {
#pragma unroll
      for (int j = 0; j < 2; ++j) {
        bf16x8 bfr = *(const bf16x8*)(Bs + g * 2048 + (wn + j * 16 + fr) * 32 + fk);
#pragma unroll
        for (int i = 0; i < 4; ++i)
          acc[g][i][j] = __builtin_amdgcn_mfma_f32_16x16x32_bf16(
              af[i], bfr, acc[g][i][j], 0, 0, 0);
      }
    }
    __syncthreads();
  }

  // Epilogue: per-(lane,reg) element indices from the calibration probes.
#pragma unroll
  for (int j = 0; j < 2; ++j) {
#pragma unroll
    for (int i = 0; i < 4; ++i) {
#pragma unroll
      for (int r = 0; r < 4; ++r) {
        const int m = m0 + wm + i * 16 + mhat[r];
        const int n = n0 + wn + j * 16 + nhat[r];
        const size_t idx = (size_t)m * HS + n;
        const float gi = acc[0][i][j][r] + b_ii[n] + b_hi[n];
        const float gf = acc[1][i][j][r] + b_if[n] + b_hf[n];
        const float gg = acc[2][i][j][r] + b_ig[n] + b_hg[n];
        const float it = 1.f / (1.f + __expf(-gi));
        const float ft = 1.f / (1.f + __expf(-gf));
        const float e2 = __expf(-2.f * gg);
        const float gt = (1.f - e2) / (1.f + e2);  // tanh
        out[idx] = ft * c[idx] + it * gt;          // fp32 store
      }
    }
  }
}

extern "C" void kernel_launch(void* const* d_in, const int* in_sizes, int n_in,
                              void* d_out, int out_size, void* d_ws, size_t ws_size,
                              hipStream_t stream) {
  const float* x  = (const float*)d_in[0];
  const float* h  = (const float*)d_in[1];
  const float* c  = (const float*)d_in[2];
  const float* w_ii = (const float*)d_in[3];
  const float* b_ii = (const float*)d_in[4];
  const float* w_hi = (const float*)d_in[5];
  const float* b_hi = (const float*)d_in[6];
  const float* w_if = (const float*)d_in[7];
  const float* b_if = (const float*)d_in[8];
  const float* w_hf = (const float*)d_in[9];
  const float* b_hf = (const float*)d_in[10];
  const float* w_ig = (const float*)d_in[11];
  const float* b_ig = (const float*)d_in[12];
  const float* w_hg = (const float*)d_in[13];
  const float* b_hg = (const float*)d_in[14];
  float* out = (float*)d_out;

  dim3 grid(2048);   // 128 M-tiles x 16 N-tiles
  dim3 block(256);
  hipLaunchKernelGGL(lstm_fused, grid, block, 0, stream,
                     x, h, c, w_ii, w_hi, w_if, w_hf, w_ig, w_hg,
                     b_ii, b_hi, b_if, b_hf, b_ig, b_hg, out);
}

// Round 5
// 697.875 us; speedup vs baseline: 1.3625x; 1.3625x over previous
//
#include <hip/hip_runtime.h>

// LSTM cell: fp32 inputs, fp32 output (bf16-lenient compare).
// gates[B,3H] = x@Wx^T + h@Wh^T + b; new_c = sig(gf)*c + sig(gi)*tanh(gg).
// M=16384, N=1024 x 3 gates, K=2048.
// MFMA 32x32x16 bf16; fp32->bf16 convert in registers during staging.
// Block = 128M x 64N x 3 gates, 256 thr = 4 waves (2x2), wave = 64M x 32N x 3.
// Software-pipelined: global prefetch regs + LDS double buffer, 1 barrier/iter.

#define HS      1024
#define K_TOTAL 2048
#define BK      32
#define NITER   (K_TOTAL / BK)   // 64

typedef __bf16 bf16;
typedef bf16  bf16x4  __attribute__((ext_vector_type(4)));
typedef bf16  bf16x8  __attribute__((ext_vector_type(8)));
typedef float f32x4   __attribute__((ext_vector_type(4)));
typedef float f32x16  __attribute__((ext_vector_type(16)));

// Panel = 64 rows x 32 cols fp32 (row stride ld) -> bf16 LDS [64][32].
// 512 f32x4 chunks, 2 per thread.
__device__ __forceinline__ void ldpanel(const float* __restrict__ src, int tid,
                                        f32x4* __restrict__ v) {
#pragma unroll
  for (int b = 0; b < 2; ++b) {
    const int cc  = tid + b * 256;
    const int row = cc >> 3;
    const int col = (cc & 7) * 4;
    v[b] = *(const f32x4*)(src + (size_t)row * HS + col);
  }
}

__device__ __forceinline__ void stpanel(bf16* __restrict__ dst, int tid,
                                        const f32x4* __restrict__ v) {
#pragma unroll
  for (int b = 0; b < 2; ++b) {
    const int cc  = tid + b * 256;
    const int row = cc >> 3;
    const int col = (cc & 7) * 4;
    bf16x4 o;
    o[0] = (bf16)v[b][0]; o[1] = (bf16)v[b][1];
    o[2] = (bf16)v[b][2]; o[3] = (bf16)v[b][3];
    *(bf16x4*)(dst + row * 32 + col) = o;
  }
}

__device__ __forceinline__ void get_srcs(
    int k, int m0, int n0,
    const float* __restrict__ x, const float* __restrict__ h,
    const float* __restrict__ w_ii, const float* __restrict__ w_hi,
    const float* __restrict__ w_if, const float* __restrict__ w_hf,
    const float* __restrict__ w_ig, const float* __restrict__ w_hg,
    const float* s[5]) {
  const int kk = k * BK;
  const float* Ag; const float* w0; const float* w1; const float* w2; int kl;
  if (kk < 1024) { Ag = x; w0 = w_ii; w1 = w_if; w2 = w_ig; kl = kk; }
  else           { Ag = h; w0 = w_hi; w1 = w_hf; w2 = w_hg; kl = kk - 1024; }
  s[0] = Ag + (size_t)m0 * HS + kl;
  s[1] = Ag + (size_t)(m0 + 64) * HS + kl;
  s[2] = w0 + (size_t)n0 * HS + kl;
  s[3] = w1 + (size_t)n0 * HS + kl;
  s[4] = w2 + (size_t)n0 * HS + kl;
}

__global__ __launch_bounds__(256, 2) void lstm_fused(
    const float* __restrict__ x, const float* __restrict__ h,
    const float* __restrict__ c,
    const float* __restrict__ w_ii, const float* __restrict__ w_hi,
    const float* __restrict__ w_if, const float* __restrict__ w_hf,
    const float* __restrict__ w_ig, const float* __restrict__ w_hg,
    const float* __restrict__ b_ii, const float* __restrict__ b_hi,
    const float* __restrict__ b_if, const float* __restrict__ b_hf,
    const float* __restrict__ b_ig, const float* __restrict__ b_hg,
    float* __restrict__ out)
{
  // Double-buffered: per buf As[128][32] (4096) + Bs[3][64][32] (6144).
  __shared__ bf16 smem[2 * 10240];   // 40 KB

  const int tid  = threadIdx.x;
  const int lane = tid & 63;
  const int wave = tid >> 6;

  const int bid = blockIdx.x;
  const int nt  = bid & 15;    // nt-major: 16 consecutive blocks share A-panel
  const int mt  = bid >> 4;
  const int m0  = mt * 128;
  const int n0  = nt * 64;
  const int wm  = (wave & 1) * 64;
  const int wn  = (wave >> 1) * 32;

  f32x16 acc[3][2] = {};   // [gate][m-tile of 32]

  // ---- prologue: stage tile 0 into buf 0 ----
  {
    const float* s[5];
    get_srcs(0, m0, n0, x, h, w_ii, w_hi, w_if, w_hf, w_ig, w_hg, s);
    f32x4 pf[5][2];
#pragma unroll
    for (int p = 0; p < 5; ++p) ldpanel(s[p], tid, pf[p]);
    bf16* A0 = smem;
#pragma unroll
    for (int p = 0; p < 5; ++p) stpanel(A0 + p * 2048, tid, pf[p]);
    __syncthreads();
  }

  const int fr  = lane & 31;        // row/col within 32-tile
  const int fk8 = (lane >> 5) * 8;  // k sub-offset

  for (int k = 0; k < NITER; ++k) {
    bf16* As = smem + (k & 1) * 10240;
    bf16* Bs = As + 4096;

    // issue next tile's global loads early
    f32x4 nf[5][2];
    if (k < NITER - 1) {
      const float* s[5];
      get_srcs(k + 1, m0, n0, x, h, w_ii, w_hi, w_if, w_hf, w_ig, w_hg, s);
#pragma unroll
      for (int p = 0; p < 5; ++p) ldpanel(s[p], tid, nf[p]);
    }

    // MFMA on current tile: 2 k-steps x (2 m-tiles x 3 gates)
#pragma unroll
    for (int ks = 0; ks < 2; ++ks) {
      const int co = ks * 16 + fk8;
      bf16x8 a0 = *(const bf16x8*)(As + (wm + fr) * 32 + co);
      bf16x8 a1 = *(const bf16x8*)(As + (wm + 32 + fr) * 32 + co);
#pragma unroll
      for (int g = 0; g < 3; ++g) {
        bf16x8 b = *(const bf16x8*)(Bs + g * 2048 + (wn + fr) * 32 + co);
        acc[g][0] = __builtin_amdgcn_mfma_f32_32x32x16_bf16(a0, b, acc[g][0], 0, 0, 0);
        acc[g][1] = __builtin_amdgcn_mfma_f32_32x32x16_bf16(a1, b, acc[g][1], 0, 0, 0);
      }
    }

    // convert + write next tile into the other buffer
    if (k < NITER - 1) {
      bf16* An = smem + ((k + 1) & 1) * 10240;
#pragma unroll
      for (int p = 0; p < 5; ++p) stpanel(An + p * 2048, tid, nf[p]);
    }
    __syncthreads();
  }

  // ---- epilogue ----
  // C/D layout (32x32): col n = lane&31, row m = (r&3) + 8*(r>>2) + 4*(lane>>5).
  const int n   = n0 + wn + (lane & 31);
  const int rb  = (lane >> 5) * 4;
  const float bi  = b_ii[n] + b_hi[n];
  const float bf_ = b_if[n] + b_hf[n];
  const float bg  = b_ig[n] + b_hg[n];
#pragma unroll
  for (int i = 0; i < 2; ++i) {
#pragma unroll
    for (int r = 0; r < 16; ++r) {
      const int m = m0 + wm + i * 32 + (r & 3) + 8 * (r >> 2) + rb;
      const size_t idx = (size_t)m * HS + n;
      const float gi = acc[0][i][r] + bi;
      const float gf = acc[1][i][r] + bf_;
      const float gg = acc[2][i][r] + bg;
      const float it = 1.f / (1.f + __expf(-gi));
      const float ft = 1.f / (1.f + __expf(-gf));
      const float e2 = __expf(-2.f * gg);
      const float gt = (1.f - e2) / (1.f + e2);  // tanh
      out[idx] = ft * c[idx] + it * gt;
    }
  }
}

extern "C" void kernel_launch(void* const* d_in, const int* in_sizes, int n_in,
                              void* d_out, int out_size, void* d_ws, size_t ws_size,
                              hipStream_t stream) {
  const float* x  = (const float*)d_in[0];
  const float* h  = (const float*)d_in[1];
  const float* c  = (const float*)d_in[2];
  const float* w_ii = (const float*)d_in[3];
  const float* b_ii = (const float*)d_in[4];
  const float* w_hi = (const float*)d_in[5];
  const float* b_hi = (const float*)d_in[6];
  const float* w_if = (const float*)d_in[7];
  const float* b_if = (const float*)d_in[8];
  const float* w_hf = (const float*)d_in[9];
  const float* b_hf = (const float*)d_in[10];
  const float* w_ig = (const float*)d_in[11];
  const float* b_ig = (const float*)d_in[12];
  const float* w_hg = (const float*)d_in[13];
  const float* b_hg = (const float*)d_in[14];
  float* out = (float*)d_out;

  dim3 grid(2048);   // 16 nt x 128 mt, nt-major
  dim3 block(256);
  hipLaunchKernelGGL(lstm_fused, grid, block, 0, stream,
                     x, h, c, w_ii, w_hi, w_if, w_hf, w_ig, w_hg,
                     b_ii, b_hi, b_if, b_hf, b_ig, b_hg, out);
}